// Round 9
// baseline (92.451 us; speedup 1.0000x reference)
//
#include <hip/hip_runtime.h>
#include <hip/hip_bf16.h>

#define N_PTS 4096
#define M_PTS 16384
#define CIN   256
#define CSK   128
#define KDIM  384   // CIN + CSK
#define HDIM  256
#define NSHARD 32
#define SHPTS (N_PTS / NSHARD)   // 128

typedef unsigned int  u32;
typedef unsigned short u16;
typedef __attribute__((ext_vector_type(8))) short bf16x8;
typedef __attribute__((ext_vector_type(4))) float f32x4;

__device__ __forceinline__ u16 f2bf(float f) {
    union { float f; u32 i; } w; w.f = f;
    u32 x = w.i;
    u32 r = x + 0x7fffu + ((x >> 16) & 1u);   // RTNE
    return (u16)(r >> 16);
}

// strict "better" with lower-index tie-break (stable-sort semantics)
__device__ __forceinline__ bool ltk(float s, int p, float t, int i) {
    return (s < t) || (s == t && p < i);
}
__device__ __forceinline__ void ins3(float s, int p,
                                     float& t0, float& t1, float& t2,
                                     int& i0, int& i1, int& i2) {
    if (ltk(s, p, t2, i2)) {
        if (ltk(s, p, t1, i1)) {
            t2 = t1; i2 = i1;
            if (ltk(s, p, t0, i0)) { t1 = t0; i1 = i0; t0 = s; i0 = p; }
            else                   { t1 = s;  i1 = p; }
        } else { t2 = s; i2 = p; }
    }
}

// branchless sorted top-3 insert, strict < (ascending-index stream => stable)
#define INS3BL(s, p, t0, t1, t2, i0, i1, i2)                              \
    {                                                                     \
        float _o0 = t0, _o1 = t1, _o2 = t2;                               \
        int _a0 = i0, _a1 = i1, _a2 = i2;                                 \
        bool _c0 = (s) < _o0, _c1 = (s) < _o1, _c2 = (s) < _o2;           \
        t0 = _c0 ? (s) : _o0;              i0 = _c0 ? (p) : _a0;          \
        t1 = _c0 ? _o0 : (_c1 ? (s) : _o1); i1 = _c0 ? _a0 : (_c1 ? (p) : _a1); \
        t2 = _c1 ? _o1 : (_c2 ? (s) : _o2); i2 = _c1 ? _a1 : (_c2 ? (p) : _a2); \
    }

// branchless top-3 insert: values via min/med3 (3 VALU), indices via cmp+sel.
// Exactly equivalent to INS3BL incl. tie handling (strict <, stable).
#define INS3MM(s, p, t0, t1, t2, i0, i1, i2)                              \
    {                                                                     \
        bool _c0 = (s) < t0, _c1 = (s) < t1, _c2 = (s) < t2;              \
        int _oi0 = i0, _oi1 = i1;                                         \
        i0 = _c0 ? (p) : i0;                                              \
        i1 = _c0 ? _oi0 : (_c1 ? (p) : i1);                               \
        i2 = _c1 ? _oi1 : (_c2 ? (p) : i2);                               \
        float _ot0 = t0, _ot1 = t1;                                       \
        t0 = fminf(t0, (s));                                              \
        t1 = __builtin_amdgcn_fmed3f(_ot0, t1, (s));                      \
        t2 = __builtin_amdgcn_fmed3f(_ot1, t2, (s));                      \
    }

// ---------------------------------------------------------------------------
// Kernel 0: W1 [384][256] f32 -> W1T [256][384] bf16 (transposed, RTNE)
// ---------------------------------------------------------------------------
__global__ __launch_bounds__(384) void prep_w1t(
    const float* __restrict__ W1, u16* __restrict__ W1T)
{
    const int n = blockIdx.x;       // 256 blocks
    const int k = threadIdx.x;      // 384 threads
    W1T[(size_t)n * KDIM + k] = f2bf(W1[(size_t)k * HDIM + n]);
}

// ---------------------------------------------------------------------------
// Kernel 1: sharded 3-NN scan. TWO queries per thread (each LDS point read
// serves both -> LDS pipe traffic halved); per query 2 interleaved chains.
// Bit-exact fp32 d^2 = (|q|^2 - 2*fma(qz,pz,fma(qy,py,qx*px))) + |p|^2.
// Output TRANSPOSED: candT[(sh*3+k)*M + m].
// ---------------------------------------------------------------------------
__global__ __launch_bounds__(256, 4) void knn_scan(
    const float* __restrict__ pos,
    const float* __restrict__ pos_skip,
    uint2* __restrict__ candT)
{
    __shared__ float4 spts[SHPTS];     // 128 x 16B = 2 KB
    const int tid = threadIdx.x;
    const int sh = blockIdx.y;
    const int pbase = sh * SHPTS;
    const int qbase = blockIdx.x * 512;
    const int m0 = qbase + tid;
    const int m1 = qbase + 256 + tid;

    if (tid < SHPTS) {
        const int i = pbase + tid;
        float px = pos[3 * i], py = pos[3 * i + 1], pz = pos[3 * i + 2];
        float pn = __fadd_rn(__fadd_rn(__fmul_rn(px, px), __fmul_rn(py, py)),
                             __fmul_rn(pz, pz));
        spts[tid] = make_float4(px, py, pz, pn);
    }

    const float qx0 = pos_skip[3 * m0];
    const float qy0 = pos_skip[3 * m0 + 1];
    const float qz0 = pos_skip[3 * m0 + 2];
    const float qn0 = __fadd_rn(__fadd_rn(__fmul_rn(qx0, qx0), __fmul_rn(qy0, qy0)),
                                __fmul_rn(qz0, qz0));
    const float qx1 = pos_skip[3 * m1];
    const float qy1 = pos_skip[3 * m1 + 1];
    const float qz1 = pos_skip[3 * m1 + 2];
    const float qn1 = __fadd_rn(__fadd_rn(__fmul_rn(qx1, qx1), __fmul_rn(qy1, qy1)),
                                __fmul_rn(qz1, qz1));
    __syncthreads();

    // state: [query][chain]  (all indices compile-time constant after unroll)
    float e0[2][2], e1[2][2], e2[2][2];
    int   a0[2][2], a1[2][2], a2[2][2];
    #pragma unroll
    for (int q = 0; q < 2; ++q)
        #pragma unroll
        for (int c = 0; c < 2; ++c) {
            e0[q][c] = 3.4e38f; e1[q][c] = 3.4e38f; e2[q][c] = 3.4e38f;
            a0[q][c] = 0x7fffffff; a1[q][c] = 0x7fffffff; a2[q][c] = 0x7fffffff;
        }

    #pragma unroll 8
    for (int j = 0; j < SHPTS; ++j) {
        float4 v = spts[j];            // wave-uniform broadcast read
        const int p = pbase + j;
        const int c = j & 1;           // constant per unrolled body
        {
            float b = __fmaf_rn(qz0, v.z, __fmaf_rn(qy0, v.y, __fmul_rn(qx0, v.x)));
            float s = __fadd_rn(__fmaf_rn(-2.0f, b, qn0), v.w);
            INS3MM(s, p, e0[0][c], e1[0][c], e2[0][c], a0[0][c], a1[0][c], a2[0][c]);
        }
        {
            float b = __fmaf_rn(qz1, v.z, __fmaf_rn(qy1, v.y, __fmul_rn(qx1, v.x)));
            float s = __fadd_rn(__fmaf_rn(-2.0f, b, qn1), v.w);
            INS3MM(s, p, e0[1][c], e1[1][c], e2[1][c], a0[1][c], a1[1][c], a2[1][c]);
        }
    }

    // merge chain 1 into chain 0 per query (value, then lower-index tie-break)
    #pragma unroll
    for (int q = 0; q < 2; ++q) {
        ins3(e0[q][1], a0[q][1], e0[q][0], e1[q][0], e2[q][0], a0[q][0], a1[q][0], a2[q][0]);
        ins3(e1[q][1], a1[q][1], e0[q][0], e1[q][0], e2[q][0], a0[q][0], a1[q][0], a2[q][0]);
        ins3(e2[q][1], a2[q][1], e0[q][0], e1[q][0], e2[q][0], a0[q][0], a1[q][0], a2[q][0]);
    }

    candT[(size_t)(sh * 3 + 0) * M_PTS + m0] = make_uint2(__float_as_uint(e0[0][0]), (u32)a0[0][0]);
    candT[(size_t)(sh * 3 + 1) * M_PTS + m0] = make_uint2(__float_as_uint(e1[0][0]), (u32)a1[0][0]);
    candT[(size_t)(sh * 3 + 2) * M_PTS + m0] = make_uint2(__float_as_uint(e2[0][0]), (u32)a2[0][0]);
    candT[(size_t)(sh * 3 + 0) * M_PTS + m1] = make_uint2(__float_as_uint(e0[1][0]), (u32)a0[1][0]);
    candT[(size_t)(sh * 3 + 1) * M_PTS + m1] = make_uint2(__float_as_uint(e1[1][0]), (u32)a1[1][0]);
    candT[(size_t)(sh * 3 + 2) * M_PTS + m1] = make_uint2(__float_as_uint(e2[1][0]), (u32)a2[1][0]);
}

// ---------------------------------------------------------------------------
// Kernel 2: per-lane merge of 32 shard top-3 lists -> normalized weights+idx.
// Shard-ascending + k-ascending insert order with strict < == stable order.
// ---------------------------------------------------------------------------
__global__ __launch_bounds__(256) void knn_merge(
    const uint2* __restrict__ candT,   // [32][3][M]
    float4* __restrict__ nbrw,         // [M] (w0,w1,w2,-) normalized
    uint4* __restrict__ nbri)          // [M] (i0,i1,i2,-)
{
    const int m = blockIdx.x * 256 + threadIdx.x;

    float t0 = 3.4e38f, t1 = 3.4e38f, t2 = 3.4e38f;
    int   i0 = 0x7fffffff, i1 = 0x7fffffff, i2 = 0x7fffffff;

    #pragma unroll
    for (int sh = 0; sh < NSHARD; ++sh) {
        #pragma unroll
        for (int k = 0; k < 3; ++k) {
            uint2 v = candT[(size_t)(sh * 3 + k) * M_PTS + m];
            float s = __uint_as_float(v.x);
            const int p = (int)v.y;
            INS3BL(s, p, t0, t1, t2, i0, i1, i2);
        }
    }

    float w0 = __fdiv_rn(1.0f, fmaxf(t0, 1e-16f));
    float w1 = __fdiv_rn(1.0f, fmaxf(t1, 1e-16f));
    float w2 = __fdiv_rn(1.0f, fmaxf(t2, 1e-16f));
    float inv = __fdiv_rn(1.0f, __fadd_rn(__fadd_rn(w0, w1), w2));
    nbrw[m] = make_float4(w0 * inv, w1 * inv, w2 * inv, 0.f);
    nbri[m] = make_uint4((u32)i0, (u32)i1, (u32)i2, 0u);
}

// ---------------------------------------------------------------------------
// Kernel 3 (MFMA): Z = bf16(x) @ bf16(W1[:256,:])   [4096, 256], no bias.
// B staged from pre-converted W1T (vector 16B load + ds_write_b128).
// ---------------------------------------------------------------------------
__global__ __launch_bounds__(256) void gemm_Z(
    const float* __restrict__ x, const u16* __restrict__ W1T,
    float* __restrict__ Z)
{
    __shared__ alignas(16) u16 Bs[64][40];
    const int tid = threadIdx.x;
    const int w = tid >> 6, l = tid & 63;
    const int bm = blockIdx.x * 128;
    const int bn = blockIdx.y * 64;
    const int lr = l & 15, lg = l >> 4;

    f32x4 acc[2][4];
    #pragma unroll
    for (int mt = 0; mt < 2; ++mt)
        #pragma unroll
        for (int nt = 0; nt < 4; ++nt)
            acc[mt][nt] = (f32x4){0.f, 0.f, 0.f, 0.f};

    const int sc = tid >> 2;
    const int sk = (tid & 3) * 8;

    for (int k0 = 0; k0 < CIN; k0 += 32) {
        *reinterpret_cast<bf16x8*>(&Bs[sc][sk]) =
            *reinterpret_cast<const bf16x8*>(&W1T[(size_t)(bn + sc) * KDIM + k0 + sk]);
        __syncthreads();

        bf16x8 af[2];
        #pragma unroll
        for (int mt = 0; mt < 2; ++mt) {
            const float* xp = x + (size_t)(bm + w * 32 + mt * 16 + lr) * CIN + k0 + lg * 8;
            float4 h0 = *reinterpret_cast<const float4*>(xp);
            float4 h1 = *reinterpret_cast<const float4*>(xp + 4);
            af[mt][0] = (short)f2bf(h0.x); af[mt][1] = (short)f2bf(h0.y);
            af[mt][2] = (short)f2bf(h0.z); af[mt][3] = (short)f2bf(h0.w);
            af[mt][4] = (short)f2bf(h1.x); af[mt][5] = (short)f2bf(h1.y);
            af[mt][6] = (short)f2bf(h1.z); af[mt][7] = (short)f2bf(h1.w);
        }
        #pragma unroll
        for (int nt = 0; nt < 4; ++nt) {
            bf16x8 bf = *reinterpret_cast<const bf16x8*>(&Bs[nt * 16 + lr][lg * 8]);
            #pragma unroll
            for (int mt = 0; mt < 2; ++mt)
                acc[mt][nt] = __builtin_amdgcn_mfma_f32_16x16x32_bf16(
                    af[mt], bf, acc[mt][nt], 0, 0, 0);
        }
        __syncthreads();
    }

    #pragma unroll
    for (int nt = 0; nt < 4; ++nt) {
        const int col = bn + nt * 16 + lr;
        #pragma unroll
        for (int mt = 0; mt < 2; ++mt)
            #pragma unroll
            for (int i = 0; i < 4; ++i) {
                const int row = bm + w * 32 + mt * 16 + lg * 4 + i;
                Z[(size_t)row * HDIM + col] = acc[mt][nt][i];
            }
    }
}

// ---------------------------------------------------------------------------
// Kernel 4 (MFMA): S = bf16(x_skip) @ bf16(W1[256:,:]); epilogue fuses the
// knn interpolation: H = relu(S + sum_k w_k Z[i_k] + b1), H stored bf16.
// ---------------------------------------------------------------------------
__global__ __launch_bounds__(256) void gemm_SH(
    const float* __restrict__ x_skip, const u16* __restrict__ W1T,
    const float* __restrict__ b1, const float* __restrict__ Z,
    const float4* __restrict__ nbrw, const uint4* __restrict__ nbri,
    u16* __restrict__ H)
{
    __shared__ alignas(16) u16 Bs[64][40];
    const int tid = threadIdx.x;
    const int w = tid >> 6, l = tid & 63;
    const int bm = blockIdx.x * 128;
    const int bn = blockIdx.y * 64;
    const int lr = l & 15, lg = l >> 4;

    f32x4 acc[2][4];
    #pragma unroll
    for (int mt = 0; mt < 2; ++mt)
        #pragma unroll
        for (int nt = 0; nt < 4; ++nt)
            acc[mt][nt] = (f32x4){0.f, 0.f, 0.f, 0.f};

    const int sc = tid >> 2;
    const int sk = (tid & 3) * 8;

    for (int k0 = 0; k0 < CSK; k0 += 32) {
        *reinterpret_cast<bf16x8*>(&Bs[sc][sk]) =
            *reinterpret_cast<const bf16x8*>(&W1T[(size_t)(bn + sc) * KDIM + CIN + k0 + sk]);
        __syncthreads();

        bf16x8 af[2];
        #pragma unroll
        for (int mt = 0; mt < 2; ++mt) {
            const float* xp = x_skip + (size_t)(bm + w * 32 + mt * 16 + lr) * CSK + k0 + lg * 8;
            float4 h0 = *reinterpret_cast<const float4*>(xp);
            float4 h1 = *reinterpret_cast<const float4*>(xp + 4);
            af[mt][0] = (short)f2bf(h0.x); af[mt][1] = (short)f2bf(h0.y);
            af[mt][2] = (short)f2bf(h0.z); af[mt][3] = (short)f2bf(h0.w);
            af[mt][4] = (short)f2bf(h1.x); af[mt][5] = (short)f2bf(h1.y);
            af[mt][6] = (short)f2bf(h1.z); af[mt][7] = (short)f2bf(h1.w);
        }
        #pragma unroll
        for (int nt = 0; nt < 4; ++nt) {
            bf16x8 bf = *reinterpret_cast<const bf16x8*>(&Bs[nt * 16 + lr][lg * 8]);
            #pragma unroll
            for (int mt = 0; mt < 2; ++mt)
                acc[mt][nt] = __builtin_amdgcn_mfma_f32_16x16x32_bf16(
                    af[mt], bf, acc[mt][nt], 0, 0, 0);
        }
        __syncthreads();
    }

    // epilogue: blend interpolated Z rows + bias + relu -> H (bf16)
    #pragma unroll
    for (int mt = 0; mt < 2; ++mt) {
        #pragma unroll
        for (int i = 0; i < 4; ++i) {
            const int row = bm + w * 32 + mt * 16 + lg * 4 + i;
            const float4 wv = nbrw[row];
            const uint4  iv = nbri[row];
            const float* z0 = Z + (size_t)iv.x * HDIM;
            const float* z1 = Z + (size_t)iv.y * HDIM;
            const float* z2 = Z + (size_t)iv.z * HDIM;
            #pragma unroll
            for (int nt = 0; nt < 4; ++nt) {
                const int col = bn + nt * 16 + lr;
                float zb = wv.x * z0[col] + wv.y * z1[col] + wv.z * z2[col];
                float v = acc[mt][nt][i] + zb + b1[col];
                H[(size_t)row * HDIM + col] = f2bf(v > 0.f ? v : 0.f);
            }
        }
    }
}

// ---------------------------------------------------------------------------
// Kernel 5 (MFMA): out = H @ W2 + b2.  H bf16 [16384,256], out f32.
// ---------------------------------------------------------------------------
__global__ __launch_bounds__(256) void gemm2_mfma(
    const u16* __restrict__ H, const float* __restrict__ W2,
    const float* __restrict__ b2, float* __restrict__ out)
{
    __shared__ alignas(16) u16 Bs[64][40];
    const int tid = threadIdx.x;
    const int w = tid >> 6, l = tid & 63;
    const int bm = blockIdx.x * 128;
    const int bn = blockIdx.y * 64;
    const int lr = l & 15, lg = l >> 4;

    f32x4 acc[2][4];
    #pragma unroll
    for (int mt = 0; mt < 2; ++mt)
        #pragma unroll
        for (int nt = 0; nt < 4; ++nt)
            acc[mt][nt] = (f32x4){0.f, 0.f, 0.f, 0.f};

    const int sc = tid >> 2;
    const int sk = (tid & 3) * 8;

    for (int k0 = 0; k0 < HDIM; k0 += 32) {
        #pragma unroll
        for (int j = 0; j < 8; ++j)
            Bs[sc][sk + j] = f2bf(W2[(size_t)(k0 + sk + j) * HDIM + bn + sc]);
        __syncthreads();

        bf16x8 af[2];
        #pragma unroll
        for (int mt = 0; mt < 2; ++mt) {
            const int row = bm + w * 32 + mt * 16 + lr;
            af[mt] = *reinterpret_cast<const bf16x8*>(H + (size_t)row * HDIM + k0 + lg * 8);
        }
        #pragma unroll
        for (int nt = 0; nt < 4; ++nt) {
            bf16x8 bf = *reinterpret_cast<const bf16x8*>(&Bs[nt * 16 + lr][lg * 8]);
            #pragma unroll
            for (int mt = 0; mt < 2; ++mt)
                acc[mt][nt] = __builtin_amdgcn_mfma_f32_16x16x32_bf16(
                    af[mt], bf, acc[mt][nt], 0, 0, 0);
        }
        __syncthreads();
    }

    #pragma unroll
    for (int nt = 0; nt < 4; ++nt) {
        const int col = bn + nt * 16 + lr;
        const float bias = b2[col];
        #pragma unroll
        for (int mt = 0; mt < 2; ++mt)
            #pragma unroll
            for (int i = 0; i < 4; ++i) {
                const int row = bm + w * 32 + mt * 16 + lg * 4 + i;
                out[(size_t)row * HDIM + col] = acc[mt][nt][i] + bias;
            }
    }
}

// ---------------------------------------------------------------------------
extern "C" void kernel_launch(void* const* d_in, const int* in_sizes, int n_in,
                              void* d_out, int out_size, void* d_ws, size_t ws_size,
                              hipStream_t stream) {
    const float* x        = (const float*)d_in[0];
    const float* pos      = (const float*)d_in[1];
    const float* x_skip   = (const float*)d_in[2];
    const float* pos_skip = (const float*)d_in[3];
    const float* W1       = (const float*)d_in[4];
    const float* b1       = (const float*)d_in[5];
    const float* W2       = (const float*)d_in[6];
    const float* b2       = (const float*)d_in[7];

    // d_ws (within proven 12.5 MiB): Hbuf 8M | Z 4M | nbrw 256K | nbri 256K
    u16*    Hbuf = (u16*)d_ws;                               // [16384][256] bf16
    float*  Z    = (float*)((char*)d_ws + (8u << 20));       // [4096][256] f32
    float4* nbrw = (float4*)((char*)d_ws + (12u << 20));
    uint4*  nbri = (uint4*)((char*)d_ws + (12u << 20) + (256u << 10));

    // d_out scratch (all dead before gemm2 writes out):
    uint2* candT = (uint2*)d_out;                            // [32][3][16384] = 12.58 MB
    u16*   W1T   = (u16*)((char*)d_out + (14u << 20));       // [256][384] bf16 = 192 KB
    float* out   = (float*)d_out;

    prep_w1t  <<<256, 384, 0, stream>>>(W1, W1T);
    knn_scan  <<<dim3(32, NSHARD), 256, 0, stream>>>(pos, pos_skip, candT);
    knn_merge <<<64, 256, 0, stream>>>(candT, nbrw, nbri);
    gemm_Z    <<<dim3(32, 4), 256, 0, stream>>>(x, W1T, Z);
    gemm_SH   <<<dim3(128, 4), 256, 0, stream>>>(x_skip, W1T, b1, Z, nbrw, nbri, Hbuf);
    gemm2_mfma<<<dim3(128, 4), 256, 0, stream>>>(Hbuf, W2, b2, out);
}